// Round 1
// baseline (4250.122 us; speedup 1.0000x reference)
//
#include <hip/hip_runtime.h>
#include <cstdint>

typedef __bf16 bf16_t;
typedef bf16_t bf16x8 __attribute__((ext_vector_type(8)));
typedef float f32x4 __attribute__((ext_vector_type(4)));

#define D_MODEL 1024
#define DFF_    4096
#define NLAYER  8
#define BB      4
#define SS      2048
#define MS      (BB*SS)   // 8192 rows

// ---------------- async global->LDS 16B ----------------
__device__ __forceinline__ void gload_lds16(const void* g, void* l) {
  typedef __attribute__((address_space(1))) void gv_t;
  typedef __attribute__((address_space(3))) void lv_t;
  __builtin_amdgcn_global_load_lds((gv_t*)(uintptr_t)g, (lv_t*)(uintptr_t)l, 16, 0, 0);
}

// ---------------- embedding + sinusoidal PE ----------------
__global__ __launch_bounds__(256) void embed_pe_kernel(
    const int* __restrict__ tokens, const float* __restrict__ emb,
    float* __restrict__ x) {
  int idx = blockIdx.x * 256 + threadIdx.x;      // over MS*D
  int d  = idx & (D_MODEL - 1);
  int bs = idx >> 10;
  int s  = bs & (SS - 1);
  int tok = tokens[bs];
  float e = emb[(size_t)tok * D_MODEL + d];
  int i2 = d & ~1;
  float div = __expf((float)i2 * (-9.210340371976184f / (float)D_MODEL));
  float ang = (float)s * div;
  float pe = (d & 1) ? cosf(ang) : sinf(ang);
  x[idx] = e + pe;
}

// ---------------- layernorm -> bf16 ----------------
__global__ __launch_bounds__(256) void ln_kernel(
    const float* __restrict__ xin, const float* __restrict__ g,
    const float* __restrict__ beta, bf16_t* __restrict__ out) {
  const size_t row = blockIdx.x;
  const int t = threadIdx.x;
  const float* xr = xin + row * D_MODEL;
  float4 vx = ((const float4*)xr)[t];
  float s = vx.x + vx.y + vx.z + vx.w;
#pragma unroll
  for (int o = 32; o > 0; o >>= 1) s += __shfl_down(s, o);
  __shared__ float red[8];
  const int lane = t & 63, w = t >> 6;
  if (lane == 0) red[w] = s;
  __syncthreads();
  const float mu = (red[0] + red[1] + red[2] + red[3]) * (1.f / D_MODEL);
  float d0 = vx.x - mu, d1 = vx.y - mu, d2 = vx.z - mu, d3 = vx.w - mu;
  float sq = d0 * d0 + d1 * d1 + d2 * d2 + d3 * d3;
#pragma unroll
  for (int o = 32; o > 0; o >>= 1) sq += __shfl_down(sq, o);
  if (lane == 0) red[4 + w] = sq;
  __syncthreads();
  const float var = (red[4] + red[5] + red[6] + red[7]) * (1.f / D_MODEL);
  const float rs = rsqrtf(var + 1e-5f);
  float4 gg = ((const float4*)g)[t];
  float4 bb = ((const float4*)beta)[t];
  alignas(8) bf16_t o4[4];
  o4[0] = (bf16_t)(d0 * rs * gg.x + bb.x);
  o4[1] = (bf16_t)(d1 * rs * gg.y + bb.y);
  o4[2] = (bf16_t)(d2 * rs * gg.z + bb.z);
  o4[3] = (bf16_t)(d3 * rs * gg.w + bb.w);
  *(uint2*)&out[row * D_MODEL + t * 4] = *(const uint2*)o4;
}

// ---------------- softmax (row of 2048, scale 1/32) -> bf16 ----------------
__global__ __launch_bounds__(256) void softmax_kernel(
    const float* __restrict__ sc, bf16_t* __restrict__ attn) {
  const size_t row = blockIdx.x;
  const int t = threadIdx.x;
  const float* sr = sc + row * SS;
  float4 a = ((const float4*)sr)[t];
  float4 b = ((const float4*)sr)[t + 256];
  const float scl = 0.03125f;  // 1/sqrt(1024)
  float v[8] = {a.x * scl, a.y * scl, a.z * scl, a.w * scl,
                b.x * scl, b.y * scl, b.z * scl, b.w * scl};
  float mx = v[0];
#pragma unroll
  for (int j = 1; j < 8; ++j) mx = fmaxf(mx, v[j]);
#pragma unroll
  for (int o = 32; o > 0; o >>= 1) mx = fmaxf(mx, __shfl_down(mx, o));
  __shared__ float red[8];
  const int lane = t & 63, w = t >> 6;
  if (lane == 0) red[w] = mx;
  __syncthreads();
  mx = fmaxf(fmaxf(red[0], red[1]), fmaxf(red[2], red[3]));
  float p[8];
  float sum = 0.f;
#pragma unroll
  for (int j = 0; j < 8; ++j) { p[j] = __expf(v[j] - mx); sum += p[j]; }
#pragma unroll
  for (int o = 32; o > 0; o >>= 1) sum += __shfl_down(sum, o);
  if (lane == 0) red[4 + w] = sum;
  __syncthreads();
  const float inv = 1.f / (red[4] + red[5] + red[6] + red[7]);
  alignas(16) bf16_t o8[8];
#pragma unroll
  for (int j = 0; j < 8; ++j) o8[j] = (bf16_t)(p[j] * inv);
  bf16_t* outp = attn + row * SS;
  *(uint2*)&outp[t * 4]        = *(const uint2*)&o8[0];
  *(uint2*)&outp[1024 + t * 4] = *(const uint2*)&o8[4];
}

// ---------------- transpose + cast -> bf16 : src[R,C] -> dst[C,R] ----------------
template <typename TI>
__global__ __launch_bounds__(256) void transpose_cast_kernel(
    const TI* __restrict__ src, bf16_t* __restrict__ dst, int R, int C) {
  __shared__ bf16_t tile[32][33];
  const int bx = blockIdx.x * 32, by = blockIdx.y * 32;
  const size_t off = (size_t)blockIdx.z * (size_t)R * (size_t)C;
  const int tx = threadIdx.x & 31, ty4 = threadIdx.x >> 5;  // ty4: 0..7
#pragma unroll
  for (int j = 0; j < 4; ++j) {
    int a = ty4 * 4 + j;  // row in tile
    tile[a][tx] = (bf16_t)(float)src[off + (size_t)(by + a) * C + bx + tx];
  }
  __syncthreads();
#pragma unroll
  for (int j = 0; j < 4; ++j) {
    int b = ty4 * 4 + j;  // col in tile = dst row offset
    dst[off + (size_t)(bx + b) * R + by + tx] = tile[tx][b];
  }
}

// ---------------- NT GEMM: C[M,N] = A[M,K] * Bt[N,K]^T (+bias)(+res)(relu) ----------------
// m97 structure: 128x128 tile, BK=32, 4 waves, global_load_lds width 16.
template <bool BIAS, bool RELU, bool RES, typename OUT_T>
__global__ __launch_bounds__(256) void gemm_nt(
    const bf16_t* __restrict__ A, const bf16_t* __restrict__ Bt,
    OUT_T* __restrict__ C, const float* __restrict__ bias,
    const float* __restrict__ res, int K, int lda, int ldb, int ldc,
    long long strideA, long long strideB, long long strideC) {
  __shared__ bf16_t As[128 * 32];
  __shared__ bf16_t Bs[128 * 32];
  const int tid = threadIdx.x;
  const int lane = tid & 63;
  const int wv = tid >> 6;
  const int wm = wv & 1, wn = wv >> 1;
  const long long z = blockIdx.z;
  A += z * strideA;
  Bt += z * strideB;
  C += z * strideC;
  const float* resp = RES ? (res + z * strideC) : nullptr;
  const int m0 = blockIdx.y * 128, n0 = blockIdx.x * 128;

  f32x4 acc[4][4];
#pragma unroll
  for (int i = 0; i < 4; ++i)
#pragma unroll
    for (int j = 0; j < 4; ++j) acc[i][j] = (f32x4){0.f, 0.f, 0.f, 0.f};

  const int arow = tid >> 2;          // 0..63
  const int acol = (tid & 3) * 8;     // 0,8,16,24 (bf16 elems)
  const int lm = lane & 15, quad = lane >> 4;
  const int nK = K >> 5;
  for (int kb = 0; kb < nK; ++kb) {
    const int k0 = kb * 32;
    gload_lds16(A + (size_t)(m0 + arow) * lda + k0 + acol, &As[(size_t)tid * 8]);
    gload_lds16(A + (size_t)(m0 + arow + 64) * lda + k0 + acol, &As[(size_t)(tid + 256) * 8]);
    gload_lds16(Bt + (size_t)(n0 + arow) * ldb + k0 + acol, &Bs[(size_t)tid * 8]);
    gload_lds16(Bt + (size_t)(n0 + arow + 64) * ldb + k0 + acol, &Bs[(size_t)(tid + 256) * 8]);
    __syncthreads();
    bf16x8 af[4], bfv[4];
#pragma unroll
    for (int mt = 0; mt < 4; ++mt)
      af[mt] = *(const bf16x8*)&As[(wm * 64 + mt * 16 + lm) * 32 + quad * 8];
#pragma unroll
    for (int nt = 0; nt < 4; ++nt)
      bfv[nt] = *(const bf16x8*)&Bs[(wn * 64 + nt * 16 + lm) * 32 + quad * 8];
#pragma unroll
    for (int mt = 0; mt < 4; ++mt)
#pragma unroll
      for (int nt = 0; nt < 4; ++nt)
        acc[mt][nt] = __builtin_amdgcn_mfma_f32_16x16x32_bf16(af[mt], bfv[nt], acc[mt][nt], 0, 0, 0);
    __syncthreads();
  }
  // epilogue: D[row=quad*4+r][col=lm] within each 16x16 tile
#pragma unroll
  for (int mt = 0; mt < 4; ++mt) {
#pragma unroll
    for (int nt = 0; nt < 4; ++nt) {
      const int col = n0 + wn * 64 + nt * 16 + lm;
      float bv = 0.f;
      if (BIAS) bv = bias[col];
#pragma unroll
      for (int r = 0; r < 4; ++r) {
        const int row = m0 + wm * 64 + mt * 16 + quad * 4 + r;
        float val = acc[mt][nt][r] + bv;
        if (RES) val += resp[(size_t)row * ldc + col];
        if (RELU) val = fmaxf(val, 0.f);
        C[(size_t)row * ldc + col] = (OUT_T)val;
      }
    }
  }
}

extern "C" void kernel_launch(void* const* d_in, const int* in_sizes, int n_in,
                              void* d_out, int out_size, void* d_ws, size_t ws_size,
                              hipStream_t stream) {
  const int*   tokens = (const int*)d_in[0];
  const float* emb    = (const float*)d_in[1];
  const float* Wq     = (const float*)d_in[2];
  const float* bq     = (const float*)d_in[3];
  const float* Wk     = (const float*)d_in[4];
  const float* bk     = (const float*)d_in[5];
  const float* Wv     = (const float*)d_in[6];
  const float* bv     = (const float*)d_in[7];
  const float* g1     = (const float*)d_in[8];
  const float* beta1  = (const float*)d_in[9];
  const float* g2     = (const float*)d_in[10];
  const float* beta2  = (const float*)d_in[11];
  const float* W1     = (const float*)d_in[12];
  const float* bm1    = (const float*)d_in[13];
  const float* W2     = (const float*)d_in[14];
  const float* bm2    = (const float*)d_in[15];

  char* wp = (char*)d_ws;
  auto carve = [&](size_t bytes) -> void* {
    void* p = (void*)wp;
    wp += (bytes + 255) & ~(size_t)255;
    return p;
  };
  bf16_t* WqT  = (bf16_t*)carve((size_t)D_MODEL * D_MODEL * 2);
  bf16_t* WkT  = (bf16_t*)carve((size_t)D_MODEL * D_MODEL * 2);
  bf16_t* WvT  = (bf16_t*)carve((size_t)D_MODEL * D_MODEL * 2);
  bf16_t* W1T  = (bf16_t*)carve((size_t)D_MODEL * DFF_ * 2);
  bf16_t* W2T  = (bf16_t*)carve((size_t)D_MODEL * DFF_ * 2);
  float*  x    = (float*)carve((size_t)MS * D_MODEL * 4);
  bf16_t* h    = (bf16_t*)carve((size_t)MS * D_MODEL * 2);
  bf16_t* q    = (bf16_t*)carve((size_t)MS * D_MODEL * 2);
  bf16_t* kbuf = (bf16_t*)carve((size_t)MS * D_MODEL * 2);
  bf16_t* vbuf = (bf16_t*)carve((size_t)MS * D_MODEL * 2);
  float*  sc   = (float*)carve((size_t)BB * SS * SS * 4);
  bf16_t* attn = (bf16_t*)carve((size_t)BB * SS * SS * 2);
  bf16_t* vT   = q;            // reuse: q is dead after scores GEMM
  bf16_t* mbuf = (bf16_t*)sc;  // reuse: scores dead after softmax (67.1MB each)

  // embedding + positional encoding
  embed_pe_kernel<<<(MS * D_MODEL) / 256, 256, 0, stream>>>(tokens, emb, x);

  for (int i = 0; i < NLAYER; ++i) {
    const size_t wOff  = (size_t)i * D_MODEL * D_MODEL;
    const size_t w1Off = (size_t)i * D_MODEL * DFF_;
    // weight convert + transpose to [N,K] bf16
    transpose_cast_kernel<float><<<dim3(32, 32, 1), 256, 0, stream>>>(Wq + wOff, WqT, D_MODEL, D_MODEL);
    transpose_cast_kernel<float><<<dim3(32, 32, 1), 256, 0, stream>>>(Wk + wOff, WkT, D_MODEL, D_MODEL);
    transpose_cast_kernel<float><<<dim3(32, 32, 1), 256, 0, stream>>>(Wv + wOff, WvT, D_MODEL, D_MODEL);
    transpose_cast_kernel<float><<<dim3(128, 32, 1), 256, 0, stream>>>(W1 + w1Off, W1T, D_MODEL, DFF_);
    transpose_cast_kernel<float><<<dim3(32, 128, 1), 256, 0, stream>>>(W2 + w1Off, W2T, DFF_, D_MODEL);

    // LN1 -> h (bf16)
    ln_kernel<<<MS, 256, 0, stream>>>(x, g1 + i * D_MODEL, beta1 + i * D_MODEL, h);

    // q,k,v = h @ W + b   [8192,1024]
    gemm_nt<true, false, false, bf16_t><<<dim3(8, 64, 1), 256, 0, stream>>>(
        h, WqT, q, bq + i * D_MODEL, nullptr, D_MODEL, D_MODEL, D_MODEL, D_MODEL, 0, 0, 0);
    gemm_nt<true, false, false, bf16_t><<<dim3(8, 64, 1), 256, 0, stream>>>(
        h, WkT, kbuf, bk + i * D_MODEL, nullptr, D_MODEL, D_MODEL, D_MODEL, D_MODEL, 0, 0, 0);
    gemm_nt<true, false, false, bf16_t><<<dim3(8, 64, 1), 256, 0, stream>>>(
        h, WvT, vbuf, bv + i * D_MODEL, nullptr, D_MODEL, D_MODEL, D_MODEL, D_MODEL, 0, 0, 0);

    // scores = q @ k^T  per batch: [2048,2048] fp32
    gemm_nt<false, false, false, float><<<dim3(16, 16, BB), 256, 0, stream>>>(
        q, kbuf, sc, nullptr, nullptr, D_MODEL, D_MODEL, D_MODEL, SS,
        (long long)SS * D_MODEL, (long long)SS * D_MODEL, (long long)SS * SS);

    // softmax(scores/32) -> attn bf16
    softmax_kernel<<<BB * SS, 256, 0, stream>>>(sc, attn);

    // v^T per batch: [2048,1024] -> [1024,2048]
    transpose_cast_kernel<bf16_t><<<dim3(32, 64, BB), 256, 0, stream>>>(vbuf, vT, SS, D_MODEL);

    // x += attn @ v  per batch
    gemm_nt<false, false, true, float><<<dim3(8, 16, BB), 256, 0, stream>>>(
        attn, vT, x, nullptr, x, SS, SS, SS, D_MODEL,
        (long long)SS * SS, (long long)D_MODEL * SS, (long long)SS * D_MODEL);

    // LN2 -> h (bf16)
    ln_kernel<<<MS, 256, 0, stream>>>(x, g2 + i * D_MODEL, beta2 + i * D_MODEL, h);

    // m = relu(h @ W1 + bm1)  [8192,4096] bf16
    gemm_nt<true, true, false, bf16_t><<<dim3(32, 64, 1), 256, 0, stream>>>(
        h, W1T, mbuf, bm1 + i * DFF_, nullptr, D_MODEL, D_MODEL, D_MODEL, DFF_, 0, 0, 0);

    // x += m @ W2 + bm2  [8192,1024]; last layer writes d_out directly
    float* outC = (i == NLAYER - 1) ? (float*)d_out : x;
    gemm_nt<true, false, true, float><<<dim3(8, 64, 1), 256, 0, stream>>>(
        mbuf, W2T, outC, bm2 + i * D_MODEL, x, DFF_, DFF_, DFF_, D_MODEL, 0, 0, 0);
  }
}

// Round 2
// 3484.709 us; speedup vs baseline: 1.2196x; 1.2196x over previous
//
#include <hip/hip_runtime.h>
#include <cstdint>

typedef __bf16 bf16_t;
typedef bf16_t bf16x8 __attribute__((ext_vector_type(8)));
typedef float f32x4 __attribute__((ext_vector_type(4)));

#define D_MODEL 1024
#define DFF_    4096
#define NLAYER  8
#define BB      4
#define SS      2048
#define MS      (BB*SS)   // 8192 rows

// ---------------- async global->LDS 16B ----------------
__device__ __forceinline__ void gload_lds16(const void* g, void* l) {
  typedef __attribute__((address_space(1))) void gv_t;
  typedef __attribute__((address_space(3))) void lv_t;
  __builtin_amdgcn_global_load_lds((gv_t*)(uintptr_t)g, (lv_t*)(uintptr_t)l, 16, 0, 0);
}

// ---------------- embedding + sinusoidal PE ----------------
__global__ __launch_bounds__(256) void embed_pe_kernel(
    const int* __restrict__ tokens, const float* __restrict__ emb,
    float* __restrict__ x) {
  int idx = blockIdx.x * 256 + threadIdx.x;      // over MS*D
  int d  = idx & (D_MODEL - 1);
  int bs = idx >> 10;
  int s  = bs & (SS - 1);
  int tok = tokens[bs];
  float e = emb[(size_t)tok * D_MODEL + d];
  int i2 = d & ~1;
  float div = __expf((float)i2 * (-9.210340371976184f / (float)D_MODEL));
  float ang = (float)s * div;
  float pe = (d & 1) ? cosf(ang) : sinf(ang);
  x[idx] = e + pe;
}

// ---------------- layernorm -> bf16 ----------------
__global__ __launch_bounds__(256) void ln_kernel(
    const float* __restrict__ xin, const float* __restrict__ g,
    const float* __restrict__ beta, bf16_t* __restrict__ out) {
  const size_t row = blockIdx.x;
  const int t = threadIdx.x;
  const float* xr = xin + row * D_MODEL;
  float4 vx = ((const float4*)xr)[t];
  float s = vx.x + vx.y + vx.z + vx.w;
#pragma unroll
  for (int o = 32; o > 0; o >>= 1) s += __shfl_down(s, o);
  __shared__ float red[8];
  const int lane = t & 63, w = t >> 6;
  if (lane == 0) red[w] = s;
  __syncthreads();
  const float mu = (red[0] + red[1] + red[2] + red[3]) * (1.f / D_MODEL);
  float d0 = vx.x - mu, d1 = vx.y - mu, d2 = vx.z - mu, d3 = vx.w - mu;
  float sq = d0 * d0 + d1 * d1 + d2 * d2 + d3 * d3;
#pragma unroll
  for (int o = 32; o > 0; o >>= 1) sq += __shfl_down(sq, o);
  if (lane == 0) red[4 + w] = sq;
  __syncthreads();
  const float var = (red[4] + red[5] + red[6] + red[7]) * (1.f / D_MODEL);
  const float rs = rsqrtf(var + 1e-5f);
  float4 gg = ((const float4*)g)[t];
  float4 bb = ((const float4*)beta)[t];
  alignas(8) bf16_t o4[4];
  o4[0] = (bf16_t)(d0 * rs * gg.x + bb.x);
  o4[1] = (bf16_t)(d1 * rs * gg.y + bb.y);
  o4[2] = (bf16_t)(d2 * rs * gg.z + bb.z);
  o4[3] = (bf16_t)(d3 * rs * gg.w + bb.w);
  *(uint2*)&out[row * D_MODEL + t * 4] = *(const uint2*)o4;
}

// ---------------- softmax (row of 2048, scale 1/32) -> bf16 ----------------
__global__ __launch_bounds__(256) void softmax_kernel(
    const float* __restrict__ sc, bf16_t* __restrict__ attn) {
  const size_t row = blockIdx.x;
  const int t = threadIdx.x;
  const float* sr = sc + row * SS;
  float4 a = ((const float4*)sr)[t];
  float4 b = ((const float4*)sr)[t + 256];
  const float scl = 0.03125f;  // 1/sqrt(1024)
  float v[8] = {a.x * scl, a.y * scl, a.z * scl, a.w * scl,
                b.x * scl, b.y * scl, b.z * scl, b.w * scl};
  float mx = v[0];
#pragma unroll
  for (int j = 1; j < 8; ++j) mx = fmaxf(mx, v[j]);
#pragma unroll
  for (int o = 32; o > 0; o >>= 1) mx = fmaxf(mx, __shfl_down(mx, o));
  __shared__ float red[8];
  const int lane = t & 63, w = t >> 6;
  if (lane == 0) red[w] = mx;
  __syncthreads();
  mx = fmaxf(fmaxf(red[0], red[1]), fmaxf(red[2], red[3]));
  float p[8];
  float sum = 0.f;
#pragma unroll
  for (int j = 0; j < 8; ++j) { p[j] = __expf(v[j] - mx); sum += p[j]; }
#pragma unroll
  for (int o = 32; o > 0; o >>= 1) sum += __shfl_down(sum, o);
  if (lane == 0) red[4 + w] = sum;
  __syncthreads();
  const float inv = 1.f / (red[4] + red[5] + red[6] + red[7]);
  alignas(16) bf16_t o8[8];
#pragma unroll
  for (int j = 0; j < 8; ++j) o8[j] = (bf16_t)(p[j] * inv);
  bf16_t* outp = attn + row * SS;
  *(uint2*)&outp[t * 4]        = *(const uint2*)&o8[0];
  *(uint2*)&outp[1024 + t * 4] = *(const uint2*)&o8[4];
}

// ---------------- pack bq|bk|bv -> [L,3072] ----------------
__global__ __launch_bounds__(256) void pack_bias_kernel(
    const float* __restrict__ bq, const float* __restrict__ bk,
    const float* __restrict__ bv, float* __restrict__ out) {
  const int l = blockIdx.x;
#pragma unroll
  for (int j = 0; j < 4; ++j) {
    int t = j * 256 + threadIdx.x;
    out[l * 3072 + t]        = bq[l * 1024 + t];
    out[l * 3072 + 1024 + t] = bk[l * 1024 + t];
    out[l * 3072 + 2048 + t] = bv[l * 1024 + t];
  }
}

// ---------------- transpose + cast -> bf16 : src[R,C](ldS) -> dst[C,R](ldD) ----------------
template <typename TI>
__global__ __launch_bounds__(256) void transpose_cast_kernel(
    const TI* __restrict__ src, bf16_t* __restrict__ dst, int C,
    int ldS, int ldD, long long srcZ, long long dstZ) {
  __shared__ bf16_t tile[32][33];
  const int bx = blockIdx.x * 32, by = blockIdx.y * 32;
  const size_t soff = (size_t)blockIdx.z * (size_t)srcZ;
  const size_t doff = (size_t)blockIdx.z * (size_t)dstZ;
  const int tx = threadIdx.x & 31, ty4 = threadIdx.x >> 5;  // ty4: 0..7
#pragma unroll
  for (int j = 0; j < 4; ++j) {
    int a = ty4 * 4 + j;  // row in tile
    tile[a][tx] = (bf16_t)(float)src[soff + (size_t)(by + a) * ldS + bx + tx];
  }
  __syncthreads();
#pragma unroll
  for (int j = 0; j < 4; ++j) {
    int b = ty4 * 4 + j;  // col in tile = dst row offset
    dst[doff + (size_t)(bx + b) * ldD + by + tx] = tile[tx][b];
  }
}

// ---------------- NT GEMM: C[M,N] = A[M,K] * Bt[N,K]^T (+bias)(+res)(relu) ----------------
// 128x128 tile, BK=64, 4 waves, global_load_lds width 16, XOR-swizzled LDS
// (conflict-free ds_read_b128), XCD-chunked grouped tile mapping.
template <bool BIAS, bool RELU, bool RES, typename OUT_T>
__global__ __launch_bounds__(256) void gemm_nt(
    const bf16_t* __restrict__ A, const bf16_t* __restrict__ Bt,
    OUT_T* __restrict__ C, const float* __restrict__ bias,
    const float* __restrict__ res, int K, int lda, int ldb, int ldc,
    int nm, int nn,
    long long strideA, long long strideB, long long strideC) {
  __shared__ bf16_t As[128 * 64];
  __shared__ bf16_t Bs[128 * 64];
  const int tid = threadIdx.x;
  const int lane = tid & 63;
  const int wv = tid >> 6;
  const int wm = wv & 1, wn = wv >> 1;
  const long long z = blockIdx.y;
  A += z * strideA;
  Bt += z * strideB;
  C += z * strideC;
  const float* resp = RES ? (res + z * strideC) : nullptr;

  // ---- tile swizzle: XCD chunking + grouped (8 m-tiles per n step) ----
  int id = blockIdx.x;
  const int T = nm * nn;
  if ((T & 7) == 0) id = (id & 7) * (T >> 3) + (id >> 3);
  const int GM = 8;
  const int g = id / (GM * nn);
  const int fm = g * GM;
  const int gsz = (nm - fm < GM) ? (nm - fm) : GM;
  const int lid = id - g * (GM * nn);
  const int pm = fm + (lid % gsz);
  const int pn = lid / gsz;
  const int m0 = pm * 128, n0 = pn * 128;

  f32x4 acc[4][4];
#pragma unroll
  for (int i = 0; i < 4; ++i)
#pragma unroll
    for (int j = 0; j < 4; ++j) acc[i][j] = (f32x4){0.f, 0.f, 0.f, 0.f};

  const int lm = lane & 15, quad = lane >> 4;
  const int srow = tid >> 3;        // 0..31 (staging row within pass)
  const int schk = tid & 7;         // 16B chunk slot
  const int nK = K >> 6;
  for (int kb = 0; kb < nK; ++kb) {
    const int k0 = kb << 6;
#pragma unroll
    for (int p = 0; p < 4; ++p) {
      const int r = p * 32 + srow;
      const int cg = schk ^ (r & 7);               // XOR swizzle source pick
      gload_lds16(A + (size_t)(m0 + r) * lda + k0 + cg * 8, &As[(size_t)(p * 256 + tid) * 8]);
    }
#pragma unroll
    for (int p = 0; p < 4; ++p) {
      const int r = p * 32 + srow;
      const int cg = schk ^ (r & 7);
      gload_lds16(Bt + (size_t)(n0 + r) * ldb + k0 + cg * 8, &Bs[(size_t)(p * 256 + tid) * 8]);
    }
    __syncthreads();
#pragma unroll
    for (int kk = 0; kk < 2; ++kk) {
      bf16x8 af[4], bfv[4];
#pragma unroll
      for (int mt = 0; mt < 4; ++mt) {
        const int r = wm * 64 + mt * 16 + lm;
        const int c = (kk * 4 + quad) ^ (r & 7);
        af[mt] = *(const bf16x8*)&As[r * 64 + c * 8];
      }
#pragma unroll
      for (int nt = 0; nt < 4; ++nt) {
        const int r = wn * 64 + nt * 16 + lm;
        const int c = (kk * 4 + quad) ^ (r & 7);
        bfv[nt] = *(const bf16x8*)&Bs[r * 64 + c * 8];
      }
#pragma unroll
      for (int mt = 0; mt < 4; ++mt)
#pragma unroll
        for (int nt = 0; nt < 4; ++nt)
          acc[mt][nt] = __builtin_amdgcn_mfma_f32_16x16x32_bf16(af[mt], bfv[nt], acc[mt][nt], 0, 0, 0);
    }
    __syncthreads();
  }
  // epilogue: D[row=quad*4+r][col=lm] within each 16x16 tile
#pragma unroll
  for (int mt = 0; mt < 4; ++mt) {
#pragma unroll
    for (int nt = 0; nt < 4; ++nt) {
      const int col = n0 + wn * 64 + nt * 16 + lm;
      float bv = 0.f;
      if (BIAS) bv = bias[col];
#pragma unroll
      for (int r = 0; r < 4; ++r) {
        const int row = m0 + wm * 64 + mt * 16 + quad * 4 + r;
        float val = acc[mt][nt][r] + bv;
        if (RES) val += resp[(size_t)row * ldc + col];
        if (RELU) val = fmaxf(val, 0.f);
        C[(size_t)row * ldc + col] = (OUT_T)val;
      }
    }
  }
}

extern "C" void kernel_launch(void* const* d_in, const int* in_sizes, int n_in,
                              void* d_out, int out_size, void* d_ws, size_t ws_size,
                              hipStream_t stream) {
  const int*   tokens = (const int*)d_in[0];
  const float* emb    = (const float*)d_in[1];
  const float* Wq     = (const float*)d_in[2];
  const float* bq     = (const float*)d_in[3];
  const float* Wk     = (const float*)d_in[4];
  const float* bk     = (const float*)d_in[5];
  const float* Wv     = (const float*)d_in[6];
  const float* bv     = (const float*)d_in[7];
  const float* g1     = (const float*)d_in[8];
  const float* beta1  = (const float*)d_in[9];
  const float* g2     = (const float*)d_in[10];
  const float* beta2  = (const float*)d_in[11];
  const float* W1     = (const float*)d_in[12];
  const float* bm1    = (const float*)d_in[13];
  const float* W2     = (const float*)d_in[14];
  const float* bm2    = (const float*)d_in[15];

  char* wp = (char*)d_ws;
  auto carve = [&](size_t bytes) -> void* {
    void* p = (void*)wp;
    wp += (bytes + 255) & ~(size_t)255;
    return p;
  };
  bf16_t* WqkvT = (bf16_t*)carve((size_t)3 * D_MODEL * D_MODEL * 2);  // [3072,1024]
  bf16_t* W1T   = (bf16_t*)carve((size_t)D_MODEL * DFF_ * 2);
  bf16_t* W2T   = (bf16_t*)carve((size_t)D_MODEL * DFF_ * 2);
  float*  bqkv  = (float*)carve((size_t)NLAYER * 3072 * 4);
  float*  x     = (float*)carve((size_t)MS * D_MODEL * 4);
  bf16_t* h     = (bf16_t*)carve((size_t)MS * D_MODEL * 2);
  bf16_t* qkv   = (bf16_t*)carve((size_t)MS * 3072 * 2);
  float*  sc    = (float*)carve((size_t)BB * SS * SS * 4);
  bf16_t* attn  = (bf16_t*)carve((size_t)BB * SS * SS * 2);
  bf16_t* vT    = h;             // reuse: h dead after QKV gemm, rewritten by LN2
  bf16_t* mbuf  = (bf16_t*)sc;   // reuse: scores dead after softmax (64MB <= 67MB)

  // embedding + positional encoding; pack biases
  embed_pe_kernel<<<(MS * D_MODEL) / 256, 256, 0, stream>>>(tokens, emb, x);
  pack_bias_kernel<<<NLAYER, 256, 0, stream>>>(bq, bk, bv, bqkv);

  for (int i = 0; i < NLAYER; ++i) {
    const size_t wOff  = (size_t)i * D_MODEL * D_MODEL;
    const size_t w1Off = (size_t)i * D_MODEL * DFF_;
    // weight convert + transpose to [N,K] bf16 (Wq^T|Wk^T|Wv^T packed rows)
    transpose_cast_kernel<float><<<dim3(32, 32, 1), 256, 0, stream>>>(
        Wq + wOff, WqkvT, D_MODEL, D_MODEL, D_MODEL, 0, 0);
    transpose_cast_kernel<float><<<dim3(32, 32, 1), 256, 0, stream>>>(
        Wk + wOff, WqkvT + (size_t)1024 * D_MODEL, D_MODEL, D_MODEL, D_MODEL, 0, 0);
    transpose_cast_kernel<float><<<dim3(32, 32, 1), 256, 0, stream>>>(
        Wv + wOff, WqkvT + (size_t)2048 * D_MODEL, D_MODEL, D_MODEL, D_MODEL, 0, 0);
    transpose_cast_kernel<float><<<dim3(128, 32, 1), 256, 0, stream>>>(
        W1 + w1Off, W1T, DFF_, DFF_, D_MODEL, 0, 0);
    transpose_cast_kernel<float><<<dim3(32, 128, 1), 256, 0, stream>>>(
        W2 + w1Off, W2T, D_MODEL, D_MODEL, DFF_, 0, 0);

    // LN1 -> h (bf16)
    ln_kernel<<<MS, 256, 0, stream>>>(x, g1 + i * D_MODEL, beta1 + i * D_MODEL, h);

    // qkv = h @ Wqkv + bqkv   [8192,3072]
    gemm_nt<true, false, false, bf16_t><<<dim3(64 * 24, 1), 256, 0, stream>>>(
        h, WqkvT, qkv, bqkv + i * 3072, nullptr, D_MODEL, D_MODEL, D_MODEL, 3072,
        64, 24, 0, 0, 0);

    // scores = q @ k^T  per batch: [2048,2048] fp32
    gemm_nt<false, false, false, float><<<dim3(256, BB), 256, 0, stream>>>(
        qkv, qkv + 1024, sc, nullptr, nullptr, D_MODEL, 3072, 3072, SS,
        16, 16, (long long)SS * 3072, (long long)SS * 3072, (long long)SS * SS);

    // softmax(scores/32) -> attn bf16
    softmax_kernel<<<BB * SS, 256, 0, stream>>>(sc, attn);

    // v^T per batch: [2048,1024](ld 3072) -> [1024,2048]
    transpose_cast_kernel<bf16_t><<<dim3(32, 64, BB), 256, 0, stream>>>(
        qkv + 2048, vT, D_MODEL, 3072, SS, (long long)SS * 3072, (long long)D_MODEL * SS);

    // x += attn @ v  per batch
    gemm_nt<false, false, true, float><<<dim3(128, BB), 256, 0, stream>>>(
        attn, vT, x, nullptr, x, SS, SS, SS, D_MODEL,
        16, 8, (long long)SS * SS, (long long)D_MODEL * SS, (long long)SS * D_MODEL);

    // LN2 -> h (bf16)
    ln_kernel<<<MS, 256, 0, stream>>>(x, g2 + i * D_MODEL, beta2 + i * D_MODEL, h);

    // m = relu(h @ W1 + bm1)  [8192,4096] bf16
    gemm_nt<true, true, false, bf16_t><<<dim3(64 * 32, 1), 256, 0, stream>>>(
        h, W1T, mbuf, bm1 + i * DFF_, nullptr, D_MODEL, D_MODEL, D_MODEL, DFF_,
        64, 32, 0, 0, 0);

    // x += m @ W2 + bm2  [8192,1024]; last layer writes d_out directly
    float* outC = (i == NLAYER - 1) ? (float*)d_out : x;
    gemm_nt<true, false, true, float><<<dim3(64 * 8, 1), 256, 0, stream>>>(
        mbuf, W2T, outC, bm2 + i * D_MODEL, x, DFF_, DFF_, DFF_, D_MODEL,
        64, 8, 0, 0, 0);
  }
}